// Round 2
// baseline (249.516 us; speedup 1.0000x reference)
//
#include <hip/hip_runtime.h>

// Problem constants (fixed by setup_inputs)
#define NT    8           // timesteps
#define NB    16          // batch
#define FS    262144      // C*H*W (= 2^18)
#define TPB   256         // threads per block
#define BPB   64          // blocks per batch
#define GRID  (NB*BPB)    // 1024 blocks = 4/CU, all co-resident
#define CHK   4           // float4 chunks/thread -> 16 elems/thread
#define ELB   (TPB*CHK*4) // 4096 elems per block
#define SPIN_CAP (1L<<26)

// ws layout:
//   bsum double[NT][NB][BPB] @ 0      (65536 B) per-block |m| sums, stored as -bs
//                                      (sign flip => nonzero BIT pattern = ready flag,
//                                       -0.0 covers bs==0; region zeroed at launch)
//   scnt int[NT][NB]         @ 65536  (512 B)   FALLBACK spike counts (atomic path)
//   ccnt int[NB]             @ 66048  (64 B)    FALLBACK counts-done barrier
//   cnt  int[NB][NT][BPB]    @ 66624  (32768 B) FAST spike counts, stored as count+1
#define WS_SMALL 66624
#define WS_FAST  99392

__global__ __launch_bounds__(TPB, 4)
void bispike_kernel(const float* __restrict__ x,
                    const float* __restrict__ decay_p,
                    const float* __restrict__ vth_p,
                    const float* __restrict__ W1,
                    const float* __restrict__ b1,
                    const float* __restrict__ W2,
                    const float* __restrict__ b2,
                    const float* __restrict__ att_w,
                    float* __restrict__ out,
                    double* __restrict__ bsum,
                    int* __restrict__ scnt,
                    int* __restrict__ ccnt,
                    int* __restrict__ cnt,
                    int fastcnt)
{
    const int tid  = threadIdx.x;
    const int lane = tid & 63;
    const int wid  = tid >> 6;
    const int b    = blockIdx.x / BPB;
    const int bg   = blockIdx.x % BPB;

    // fp64 reference process: sigmoid, threshold, all state in double
    const double dec  = 1.0 / (1.0 + exp(-(double)decay_p[0]));
    const double vth  = (double)vth_p[0];
    const double csub = dec * vth;            // loop-invariant spike correction

    // value-encoded LDS flags (bit pattern 0 == not ready); one slot per timestep,
    // never reused -> no per-timestep reset, no __syncthreads in the main loop.
    __shared__ double wv[NT][4];   // per-wave |m| partials, stored negated
    __shared__ double dn[NT];      // per-timestep denominator (always > 0)
    if (tid < NT * 4) ((double*)wv)[tid] = 0.0;
    if (tid < NT)     dn[tid] = 0.0;
    __syncthreads();               // the only main-path block barrier

    double   u[CHK * 4];           // unnormalized membrane m_t (fp64)
    float4   xv[CHK];              // prefetched x (fp32 in memory)
    unsigned sm[NT];               // spike bits (16 used)

    {   // t=0: m_0 = x_0 (carry is zero)
        const float* p = x + (size_t)b * FS + (size_t)bg * ELB + tid * 4;
        #pragma unroll
        for (int k = 0; k < CHK; ++k) xv[k] = *(const float4*)(p + k * (TPB * 4));
    }
    double lsum = 0.0;
    #pragma unroll
    for (int k = 0; k < CHK; ++k) {
        u[k*4+0] = (double)xv[k].x; u[k*4+1] = (double)xv[k].y;
        u[k*4+2] = (double)xv[k].z; u[k*4+3] = (double)xv[k].w;
        lsum += fabs(u[k*4+0]) + fabs(u[k*4+1]) + fabs(u[k*4+2]) + fabs(u[k*4+3]);
    }

    #pragma unroll 1
    for (int t = 0; t < NT; ++t) {
        // prefetch x[t+1]; overlaps the whole exchange below
        if (t < NT - 1) {
            const float* p = x + ((size_t)(t + 1) * NB + b) * FS
                               + (size_t)bg * ELB + tid * 4;
            #pragma unroll
            for (int k = 0; k < CHK; ++k) xv[k] = *(const float4*)(p + k * (TPB * 4));
        }

        // ---- wave partial of sum |m_t| ----
        #pragma unroll
        for (int off = 32; off > 0; off >>= 1)
            lsum += __shfl_down(lsum, off, 64);
        if (lane == 0)
            __hip_atomic_store(&wv[t][wid], -lsum, __ATOMIC_RELAXED,
                               __HIP_MEMORY_SCOPE_WORKGROUP);

        if (wid == 0) {
            // intra-block gather: LDS spin on 4 value-encoded slots
            double w; long it = 0;
            for (;;) {
                w = __hip_atomic_load(&wv[t][lane & 3], __ATOMIC_RELAXED,
                                      __HIP_MEMORY_SCOPE_WORKGROUP);
                if (__all(__double_as_longlong(w) != 0)) break;
                if (++it > SPIN_CAP) break;
                __builtin_amdgcn_s_sleep(1);
            }
            w = -w;
            w += __shfl_down(w, 2, 64);
            w += __shfl_down(w, 1, 64);
            const double blk = __shfl(w, 0, 64);   // block sum, all lanes

            double* slot = bsum + (size_t)(t * NB + b) * BPB;
            if (lane == 0)
                __hip_atomic_store(slot + bg, -blk, __ATOMIC_RELAXED,
                                   __HIP_MEMORY_SCOPE_AGENT);

            // poll the other 63 blocks of this batch (own slot known locally)
            double v = 0.0; it = 0;
            for (;;) {
                if (lane != bg)
                    v = __hip_atomic_load(slot + lane, __ATOMIC_RELAXED,
                                          __HIP_MEMORY_SCOPE_AGENT);
                if (__all(lane == bg || __double_as_longlong(v) != 0)) break;
                if (++it > SPIN_CAP) break;
                __builtin_amdgcn_s_sleep(1);
            }
            double tot = (lane == bg) ? blk : -v;
            #pragma unroll
            for (int off = 32; off > 0; off >>= 1)
                tot += __shfl_down(tot, off, 64);
            if (lane == 0)
                __hip_atomic_store(&dn[t], tot / (double)FS + 1e-6,
                                   __ATOMIC_RELAXED, __HIP_MEMORY_SCOPE_WORKGROUP);
        }

        // all waves pick up the denominator from the LDS flag (denom > 0 always)
        double denom; long it2 = 0;
        for (;;) {
            denom = __hip_atomic_load(&dn[t], __ATOMIC_RELAXED,
                                      __HIP_MEMORY_SCOPE_WORKGROUP);
            if (__double_as_longlong(denom) != 0) break;
            if (++it2 > SPIN_CAP) break;
            __builtin_amdgcn_s_sleep(1);
        }

        // fused threshold + advance:
        //   s_t  = (u >= vth*D_t)            (== m/D >= vth up to ~1e-15)
        //   u'   = (dec/D_t)*u + x' - s_t*(dec*vth)
        const double thr = vth * denom;
        const double a   = dec * (1.0 / denom);
        unsigned smt = 0;
        if (t < NT - 1) {
            double nl = 0.0;
            #pragma unroll
            for (int k = 0; k < CHK; ++k) {
                const double xn0 = (double)xv[k].x, xn1 = (double)xv[k].y,
                             xn2 = (double)xv[k].z, xn3 = (double)xv[k].w;
                double un;
                bool s0 = (u[k*4+0] >= thr); if (s0) smt |= 1u << (k*4+0);
                un = fma(a, u[k*4+0], xn0); if (s0) un -= csub;
                u[k*4+0] = un; nl += fabs(un);
                bool s1 = (u[k*4+1] >= thr); if (s1) smt |= 1u << (k*4+1);
                un = fma(a, u[k*4+1], xn1); if (s1) un -= csub;
                u[k*4+1] = un; nl += fabs(un);
                bool s2 = (u[k*4+2] >= thr); if (s2) smt |= 1u << (k*4+2);
                un = fma(a, u[k*4+2], xn2); if (s2) un -= csub;
                u[k*4+2] = un; nl += fabs(un);
                bool s3 = (u[k*4+3] >= thr); if (s3) smt |= 1u << (k*4+3);
                un = fma(a, u[k*4+3], xn3); if (s3) un -= csub;
                u[k*4+3] = un; nl += fabs(un);
            }
            lsum = nl;
        } else {
            #pragma unroll
            for (int j = 0; j < CHK * 4; ++j)
                if (u[j] >= thr) smt |= 1u << j;
        }
        sm[t] = smt;
    }

    // ---- spike counts per (t,b): exact integers ----
    __shared__ int ired[NT][4];
    #pragma unroll
    for (int t = 0; t < NT; ++t) {
        int c = __popc(sm[t]);
        #pragma unroll
        for (int off = 32; off > 0; off >>= 1)
            c += __shfl_down(c, off, 64);
        if (lane == 0) ired[t][wid] = c;
    }
    __syncthreads();

    __shared__ double summ_s[NT];
    __shared__ int totc_s[NT];

    if (fastcnt) {
        // FAST: store count+1 (flag), coalesced polling, shfl-tree sums.
        if (tid < 64) {
            int* cb = cnt + b * (NT * BPB);
            if (tid < NT) {
                int tot = (ired[tid][0] + ired[tid][1])
                        + (ired[tid][2] + ired[tid][3]);
                __hip_atomic_store(cb + tid * BPB + bg, tot + 1,
                                   __ATOMIC_RELAXED, __HIP_MEMORY_SCOPE_AGENT);
            }
            int vt[NT]; long it = 0;
            for (;;) {
                bool ok = true;
                #pragma unroll
                for (int t = 0; t < NT; ++t) {
                    vt[t] = __hip_atomic_load(cb + t * BPB + tid,
                                              __ATOMIC_RELAXED,
                                              __HIP_MEMORY_SCOPE_AGENT);
                    ok = ok && (vt[t] > 0);
                }
                if (__all(ok)) break;
                if (++it > SPIN_CAP) break;
                __builtin_amdgcn_s_sleep(1);
            }
            #pragma unroll
            for (int t = 0; t < NT; ++t) {
                int s = vt[t] - 1;
                #pragma unroll
                for (int off = 32; off > 0; off >>= 1)
                    s += __shfl_down(s, off, 64);
                if (tid == 0) totc_s[t] = s;
            }
        }
        __syncthreads();
        if (tid < NT)
            summ_s[tid] = (double)totc_s[tid] / (double)FS;    // exact
    } else {
        // FALLBACK (small ws): original atomic-counter path
        if (tid < NT) {
            int tot = (ired[tid][0] + ired[tid][1]) + (ired[tid][2] + ired[tid][3]);
            __hip_atomic_fetch_add(&scnt[tid * NB + b], tot,
                                   __ATOMIC_RELEASE, __HIP_MEMORY_SCOPE_AGENT);
        }
        __syncthreads();
        if (tid == 0) {
            __hip_atomic_fetch_add(&ccnt[b], 1,
                                   __ATOMIC_RELEASE, __HIP_MEMORY_SCOPE_AGENT);
            long it = 0;
            while (__hip_atomic_load(&ccnt[b], __ATOMIC_ACQUIRE,
                                     __HIP_MEMORY_SCOPE_AGENT) < BPB
                   && it++ < SPIN_CAP)
                __builtin_amdgcn_s_sleep(4);
        }
        __syncthreads();
        if (tid < NT) {
            int c = __hip_atomic_load(&scnt[tid * NB + b],
                                      __ATOMIC_ACQUIRE, __HIP_MEMORY_SCOPE_AGENT);
            summ_s[tid] = (double)c / (double)FS;
        }
    }
    __syncthreads();

    // ---- tiny MLP attention in fp64, redundantly per block ----
    __shared__ double h_s[4 * 64];
    __shared__ double wmat_s[NT];
    {
        int nh = tid >> 6, hd = tid & 63;
        double acc = 0.0;
        #pragma unroll
        for (int t = 0; t < NT; ++t)
            acc += summ_s[t] * (double)W1[nh * 512 + hd * 8 + t];
        acc += (double)b1[nh * 64 + hd];
        h_s[tid] = fmax(acc, 0.0);
    }
    __syncthreads();
    if (tid < NT) {
        double w = 0.0;
        for (int nh = 0; nh < 4; ++nh) {
            double macc = 0.0;
            for (int hd = 0; hd < 64; ++hd)
                macc += h_s[nh * 64 + hd] * (double)W2[nh * 512 + tid * 64 + hd];
            macc += (double)b2[nh * 8 + tid];
            w += macc * (double)att_w[nh];
        }
        wmat_s[tid] = w;
    }
    __syncthreads();

    // softmax over t in fp64 (per-thread copy)
    double awr[NT];
    {
        double mx = wmat_s[0];
        #pragma unroll
        for (int t = 1; t < NT; ++t) mx = fmax(mx, wmat_s[t]);
        double ss = 0.0;
        #pragma unroll
        for (int t = 0; t < NT; ++t) { awr[t] = exp(wmat_s[t] - mx); ss += awr[t]; }
        #pragma unroll
        for (int t = 0; t < NT; ++t) awr[t] = awr[t] / ss;
    }

    // ---- out[b,f] = sum_t spike_bit * aw[t,b] (fp64 acc, fp32 store) ----
    float* po = out + (size_t)b * FS + (size_t)bg * ELB + tid * 4;
    #pragma unroll
    for (int k = 0; k < CHK; ++k) {
        double o[4] = {0.0, 0.0, 0.0, 0.0};
        #pragma unroll
        for (int t = 0; t < NT; ++t) {
            const unsigned smt = sm[t];
            o[0] += ((smt >> (k * 4 + 0)) & 1) ? awr[t] : 0.0;
            o[1] += ((smt >> (k * 4 + 1)) & 1) ? awr[t] : 0.0;
            o[2] += ((smt >> (k * 4 + 2)) & 1) ? awr[t] : 0.0;
            o[3] += ((smt >> (k * 4 + 3)) & 1) ? awr[t] : 0.0;
        }
        *(float4*)(po + k * (TPB * 4)) =
            make_float4((float)o[0], (float)o[1], (float)o[2], (float)o[3]);
    }
}

__global__ void diag_kernel(float* out, int code) {
    out[0] = 100000.0f + (float)code;
}

extern "C" void kernel_launch(void* const* d_in, const int* in_sizes, int n_in,
                              void* d_out, int out_size, void* d_ws, size_t ws_size,
                              hipStream_t stream) {
    const float* x     = (const float*)d_in[0];
    const float* decay = (const float*)d_in[1];
    const float* vth   = (const float*)d_in[2];
    const float* W1    = (const float*)d_in[3];
    const float* b1    = (const float*)d_in[4];
    const float* W2    = (const float*)d_in[5];
    const float* b2    = (const float*)d_in[6];
    const float* att   = (const float*)d_in[7];
    float* out = (float*)d_out;

    if (ws_size < WS_SMALL) {
        diag_kernel<<<1, 1, 0, stream>>>(out, 999);
        return;
    }
    const int fastcnt = (ws_size >= (size_t)WS_FAST) ? 1 : 0;

    double* bsum = (double*)d_ws;
    int*    scnt = (int*)((char*)d_ws + 65536);
    int*    ccnt = (int*)((char*)d_ws + 66048);
    int*    cnt  = (int*)((char*)d_ws + 66624);

    // control/accumulator region zeroed every launch (ws re-poisoned 0xAA)
    hipMemsetAsync(d_ws, 0, fastcnt ? WS_FAST : WS_SMALL, stream);

    hipGetLastError();  // clear stale error
    bispike_kernel<<<dim3(GRID), dim3(TPB), 0, stream>>>(
        x, decay, vth, W1, b1, W2, b2, att, out, bsum, scnt, ccnt, cnt, fastcnt);
    hipError_t err = hipGetLastError();
    if (err != hipSuccess) {
        diag_kernel<<<1, 1, 0, stream>>>(out, (int)err);
    }
}

// Round 3
// 234.768 us; speedup vs baseline: 1.0628x; 1.0628x over previous
//
#include <hip/hip_runtime.h>

// Problem constants (fixed by setup_inputs)
#define NT    8           // timesteps
#define NB    16          // batch
#define FS    262144      // C*H*W (= 2^18)
#define TPB   256         // threads per block
#define BPB   32          // blocks per batch (halved: smaller sync fan-in)
#define GRID  (NB*BPB)    // 512 blocks = 2/CU
#define CHK   8           // float4 chunks/thread -> 32 elems/thread
#define ELB   (TPB*CHK*4) // 8192 elems per block
#define SPIN_CAP (1L<<26)

// ws layout:
//   bsum double[NT][NB][BPB] @ 0      (32768 B) per-block |m| sums, stored as -bs
//                                      (sign flip => nonzero BIT pattern = ready flag)
//   scnt int[NT][NB]         @ 32768  (512 B)   FALLBACK spike counts (atomic path)
//   ccnt int[NB]             @ 33280  (64 B)    FALLBACK counts-done barrier
//   cnt  int[NB][NT][BPB]    @ 33344  (16384 B) FAST spike counts, stored as count+1
#define WS_SMALL 33344
#define WS_FAST  49728

__global__ __launch_bounds__(TPB, 2)
void bispike_kernel(const float* __restrict__ x,
                    const float* __restrict__ decay_p,
                    const float* __restrict__ vth_p,
                    const float* __restrict__ W1,
                    const float* __restrict__ b1,
                    const float* __restrict__ W2,
                    const float* __restrict__ b2,
                    const float* __restrict__ att_w,
                    float* __restrict__ out,
                    double* __restrict__ bsum,
                    int* __restrict__ scnt,
                    int* __restrict__ ccnt,
                    int* __restrict__ cnt,
                    int fastcnt)
{
    const int tid  = threadIdx.x;
    const int lane = tid & 63;
    const int wid  = tid >> 6;
    // XCD-localized batches: blockIdx % 8 == XCD (round-robin), so batch b's
    // 32 blocks all land on XCD b%8 (2 batches per XCD, 2 blocks/CU).
    const int b    = blockIdx.x % NB;
    const int bg   = blockIdx.x / NB;

    // fp64 reference process: sigmoid, threshold, all state in double
    const double dec  = 1.0 / (1.0 + exp(-(double)decay_p[0]));
    const double vth  = (double)vth_p[0];
    const double csub = dec * vth;            // loop-invariant spike correction

    double   u[CHK * 4];           // unnormalized membrane m_t (fp64)
    float4   xv[CHK];              // prefetched x (fp32 in memory)
    unsigned sm[NT];               // spike bits (32 used)

    {   // t=0: m_0 = x_0 (carry is zero)
        const float* p = x + (size_t)b * FS + (size_t)bg * ELB + tid * 4;
        #pragma unroll
        for (int k = 0; k < CHK; ++k) xv[k] = *(const float4*)(p + k * (TPB * 4));
    }
    double lsum;
    {
        double n0 = 0.0, n1 = 0.0, n2 = 0.0, n3 = 0.0;
        #pragma unroll
        for (int k = 0; k < CHK; ++k) {
            u[k*4+0] = (double)xv[k].x; n0 += fabs(u[k*4+0]);
            u[k*4+1] = (double)xv[k].y; n1 += fabs(u[k*4+1]);
            u[k*4+2] = (double)xv[k].z; n2 += fabs(u[k*4+2]);
            u[k*4+3] = (double)xv[k].w; n3 += fabs(u[k*4+3]);
        }
        lsum = (n0 + n1) + (n2 + n3);
    }

    __shared__ double dred[4];
    __shared__ double denom_s;

    #pragma unroll 1
    for (int t = 0; t < NT; ++t) {
        // prefetch x[t+1]; overlaps the whole exchange below
        if (t < NT - 1) {
            const float* p = x + ((size_t)(t + 1) * NB + b) * FS
                               + (size_t)bg * ELB + tid * 4;
            #pragma unroll
            for (int k = 0; k < CHK; ++k) xv[k] = *(const float4*)(p + k * (TPB * 4));
        }

        // ---- wave partial of sum |m_t| ----
        double ls = lsum;
        #pragma unroll
        for (int off = 32; off > 0; off >>= 1)
            ls += __shfl_down(ls, off, 64);
        if (lane == 0) dred[wid] = ls;
        __syncthreads();           // other waves now sleep at the next barrier

        if (tid < 64) {
            double bs = (dred[0] + dred[1]) + (dred[2] + dred[3]);
            double* slot = bsum + (size_t)(t * NB + b) * BPB;
            if (tid == 0)
                __hip_atomic_store(slot + bg, -bs, __ATOMIC_RELAXED,
                                   __HIP_MEMORY_SCOPE_AGENT);

            // poll the other 31 blocks; own partial substituted locally
            const int  sl  = lane & 31;
            const bool act = (lane < 32) && (sl != bg);
            double v = 0.0; long it = 0;
            for (;;) {
                if (act)
                    v = __hip_atomic_load(slot + sl, __ATOMIC_RELAXED,
                                          __HIP_MEMORY_SCOPE_AGENT);
                if (__all(!act || __double_as_longlong(v) != 0)) break;
                if (++it > SPIN_CAP) break;
                __builtin_amdgcn_s_sleep(1);
            }
            double tot = (lane >= 32) ? 0.0 : ((sl == bg) ? bs : -v);
            #pragma unroll
            for (int off = 32; off > 0; off >>= 1)
                tot += __shfl_down(tot, off, 64);
            if (tid == 0)
                denom_s = tot / (double)FS + 1e-6;   // mean is exact /2^18
        }
        __syncthreads();
        const double denom = denom_s;

        // fused threshold + advance:
        //   s_t  = (u >= vth*D_t)            (== m/D >= vth up to ~1e-15)
        //   u'   = (dec/D_t)*u + x' - s_t*(dec*vth)
        const double thr = vth * denom;
        const double a   = dec * (1.0 / denom);
        unsigned smt = 0;
        if (t < NT - 1) {
            double n0 = 0.0, n1 = 0.0, n2 = 0.0, n3 = 0.0;
            #pragma unroll
            for (int k = 0; k < CHK; ++k) {
                const double xn0 = (double)xv[k].x, xn1 = (double)xv[k].y,
                             xn2 = (double)xv[k].z, xn3 = (double)xv[k].w;
                double un;
                bool s0 = (u[k*4+0] >= thr); if (s0) smt |= 1u << (k*4+0);
                un = fma(a, u[k*4+0], xn0); if (s0) un -= csub;
                u[k*4+0] = un; n0 += fabs(un);
                bool s1 = (u[k*4+1] >= thr); if (s1) smt |= 1u << (k*4+1);
                un = fma(a, u[k*4+1], xn1); if (s1) un -= csub;
                u[k*4+1] = un; n1 += fabs(un);
                bool s2 = (u[k*4+2] >= thr); if (s2) smt |= 1u << (k*4+2);
                un = fma(a, u[k*4+2], xn2); if (s2) un -= csub;
                u[k*4+2] = un; n2 += fabs(un);
                bool s3 = (u[k*4+3] >= thr); if (s3) smt |= 1u << (k*4+3);
                un = fma(a, u[k*4+3], xn3); if (s3) un -= csub;
                u[k*4+3] = un; n3 += fabs(un);
            }
            lsum = (n0 + n1) + (n2 + n3);
        } else {
            #pragma unroll
            for (int j = 0; j < CHK * 4; ++j)
                if (u[j] >= thr) smt |= 1u << j;
        }
        sm[t] = smt;
    }

    // ---- spike counts per (t,b): exact integers ----
    __shared__ int ired[NT][4];
    #pragma unroll
    for (int t = 0; t < NT; ++t) {
        int c = __popc(sm[t]);
        #pragma unroll
        for (int off = 32; off > 0; off >>= 1)
            c += __shfl_down(c, off, 64);
        if (lane == 0) ired[t][wid] = c;
    }
    __syncthreads();

    __shared__ double summ_s[NT];
    __shared__ int totc_s[NT];

    if (fastcnt) {
        // FAST: store count+1 (flag), coalesced polling, shfl-tree sums.
        if (tid < 64) {
            int* cb = cnt + b * (NT * BPB);
            if (tid < NT) {
                int tot = (ired[tid][0] + ired[tid][1])
                        + (ired[tid][2] + ired[tid][3]);
                __hip_atomic_store(cb + tid * BPB + bg, tot + 1,
                                   __ATOMIC_RELAXED, __HIP_MEMORY_SCOPE_AGENT);
            }
            const int  sl  = lane & 31;
            const bool act = (lane < 32) && (sl != bg);
            int vt[NT]; long it = 0;
            for (;;) {
                bool ok = true;
                #pragma unroll
                for (int t = 0; t < NT; ++t) {
                    if (act) {
                        vt[t] = __hip_atomic_load(cb + t * BPB + sl,
                                                  __ATOMIC_RELAXED,
                                                  __HIP_MEMORY_SCOPE_AGENT);
                        ok = ok && (vt[t] > 0);
                    }
                }
                if (__all(ok)) break;
                if (++it > SPIN_CAP) break;
                __builtin_amdgcn_s_sleep(1);
            }
            #pragma unroll
            for (int t = 0; t < NT; ++t) {
                int s;
                if (lane >= 32)      s = 0;
                else if (sl == bg)   s = (ired[t][0] + ired[t][1])
                                       + (ired[t][2] + ired[t][3]);
                else                 s = vt[t] - 1;
                #pragma unroll
                for (int off = 32; off > 0; off >>= 1)
                    s += __shfl_down(s, off, 64);
                if (tid == 0) totc_s[t] = s;
            }
        }
        __syncthreads();
        if (tid < NT)
            summ_s[tid] = (double)totc_s[tid] / (double)FS;    // exact
    } else {
        // FALLBACK (small ws): original atomic-counter path
        if (tid < NT) {
            int tot = (ired[tid][0] + ired[tid][1]) + (ired[tid][2] + ired[tid][3]);
            __hip_atomic_fetch_add(&scnt[tid * NB + b], tot,
                                   __ATOMIC_RELEASE, __HIP_MEMORY_SCOPE_AGENT);
        }
        __syncthreads();
        if (tid == 0) {
            __hip_atomic_fetch_add(&ccnt[b], 1,
                                   __ATOMIC_RELEASE, __HIP_MEMORY_SCOPE_AGENT);
            long it = 0;
            while (__hip_atomic_load(&ccnt[b], __ATOMIC_ACQUIRE,
                                     __HIP_MEMORY_SCOPE_AGENT) < BPB
                   && it++ < SPIN_CAP)
                __builtin_amdgcn_s_sleep(4);
        }
        __syncthreads();
        if (tid < NT) {
            int c = __hip_atomic_load(&scnt[tid * NB + b],
                                      __ATOMIC_ACQUIRE, __HIP_MEMORY_SCOPE_AGENT);
            summ_s[tid] = (double)c / (double)FS;
        }
    }
    __syncthreads();

    // ---- tiny MLP attention in fp64, redundantly per block ----
    __shared__ double h_s[4 * 64];
    __shared__ double wmat_s[NT];
    {
        int nh = tid >> 6, hd = tid & 63;
        double acc = 0.0;
        #pragma unroll
        for (int t = 0; t < NT; ++t)
            acc += summ_s[t] * (double)W1[nh * 512 + hd * 8 + t];
        acc += (double)b1[nh * 64 + hd];
        h_s[tid] = fmax(acc, 0.0);
    }
    __syncthreads();
    if (tid < NT) {
        double w = 0.0;
        for (int nh = 0; nh < 4; ++nh) {
            double macc = 0.0;
            for (int hd = 0; hd < 64; ++hd)
                macc += h_s[nh * 64 + hd] * (double)W2[nh * 512 + tid * 64 + hd];
            macc += (double)b2[nh * 8 + tid];
            w += macc * (double)att_w[nh];
        }
        wmat_s[tid] = w;
    }
    __syncthreads();

    // softmax over t in fp64 (per-thread copy)
    double awr[NT];
    {
        double mx = wmat_s[0];
        #pragma unroll
        for (int t = 1; t < NT; ++t) mx = fmax(mx, wmat_s[t]);
        double ss = 0.0;
        #pragma unroll
        for (int t = 0; t < NT; ++t) { awr[t] = exp(wmat_s[t] - mx); ss += awr[t]; }
        #pragma unroll
        for (int t = 0; t < NT; ++t) awr[t] = awr[t] / ss;
    }

    // ---- out[b,f] = sum_t spike_bit * aw[t,b] (fp64 acc, fp32 store) ----
    float* po = out + (size_t)b * FS + (size_t)bg * ELB + tid * 4;
    #pragma unroll
    for (int k = 0; k < CHK; ++k) {
        double o[4] = {0.0, 0.0, 0.0, 0.0};
        #pragma unroll
        for (int t = 0; t < NT; ++t) {
            const unsigned smt = sm[t];
            o[0] += ((smt >> (k * 4 + 0)) & 1) ? awr[t] : 0.0;
            o[1] += ((smt >> (k * 4 + 1)) & 1) ? awr[t] : 0.0;
            o[2] += ((smt >> (k * 4 + 2)) & 1) ? awr[t] : 0.0;
            o[3] += ((smt >> (k * 4 + 3)) & 1) ? awr[t] : 0.0;
        }
        *(float4*)(po + k * (TPB * 4)) =
            make_float4((float)o[0], (float)o[1], (float)o[2], (float)o[3]);
    }
}

__global__ void diag_kernel(float* out, int code) {
    out[0] = 100000.0f + (float)code;
}

extern "C" void kernel_launch(void* const* d_in, const int* in_sizes, int n_in,
                              void* d_out, int out_size, void* d_ws, size_t ws_size,
                              hipStream_t stream) {
    const float* x     = (const float*)d_in[0];
    const float* decay = (const float*)d_in[1];
    const float* vth   = (const float*)d_in[2];
    const float* W1    = (const float*)d_in[3];
    const float* b1    = (const float*)d_in[4];
    const float* W2    = (const float*)d_in[5];
    const float* b2    = (const float*)d_in[6];
    const float* att   = (const float*)d_in[7];
    float* out = (float*)d_out;

    if (ws_size < WS_SMALL) {
        diag_kernel<<<1, 1, 0, stream>>>(out, 999);
        return;
    }
    const int fastcnt = (ws_size >= (size_t)WS_FAST) ? 1 : 0;

    double* bsum = (double*)d_ws;
    int*    scnt = (int*)((char*)d_ws + 32768);
    int*    ccnt = (int*)((char*)d_ws + 33280);
    int*    cnt  = (int*)((char*)d_ws + 33344);

    // control/accumulator region zeroed every launch (ws re-poisoned 0xAA)
    hipMemsetAsync(d_ws, 0, fastcnt ? WS_FAST : WS_SMALL, stream);

    hipGetLastError();  // clear stale error
    bispike_kernel<<<dim3(GRID), dim3(TPB), 0, stream>>>(
        x, decay, vth, W1, b1, W2, b2, att, out, bsum, scnt, ccnt, cnt, fastcnt);
    hipError_t err = hipGetLastError();
    if (err != hipSuccess) {
        diag_kernel<<<1, 1, 0, stream>>>(out, (int)err);
    }
}